// Round 1
// baseline (125.501 us; speedup 1.0000x reference)
//
#include <hip/hip_runtime.h>
#include <hip/hip_bf16.h>
#include <stdint.h>

#define UNITS 1024
#define IDIM  512
#define BATCH 2048
#define KTOT  1536   // UNITS + IDIM
#define NGATE 4096   // 4*UNITS
#define BK    64
#define NITER (KTOT / BK)   // 24

typedef short bf16x8 __attribute__((ext_vector_type(8)));   // 8 bf16 = 4 VGPRs
typedef float f32x4  __attribute__((ext_vector_type(4)));

#define AS3(p) ((__attribute__((address_space(3))) void*)(p))
#define AS1(p) ((const __attribute__((address_space(1))) void*)(p))

union P8 { bf16x8 v; __hip_bfloat16 e[8]; };

// ---------------------------------------------------------------------------
// prep: blocks [0,1536) cast-concat A = bf16(concat[h,x]); blocks [1536,4608)
// transpose W fp32 [1536][4096] -> Wt bf16 [4096][1536] (k-contiguous rows).
// ---------------------------------------------------------------------------
#define NBLK_A 1536
#define NBLK_T 3072

__global__ __launch_bounds__(256) void prep(
    const float* __restrict__ x, const float* __restrict__ h,
    const float* __restrict__ W,
    __hip_bfloat16* __restrict__ A, __hip_bfloat16* __restrict__ Wt) {
  __shared__ float tile[32][65];
  const int tid = threadIdx.x;
  if (blockIdx.x < NBLK_A) {
    const int id = blockIdx.x * 256 + tid;
    const int r = id / (KTOT / 8);
    const int k = (id % (KTOT / 8)) * 8;
    const float* src = (k < UNITS) ? h + (size_t)r * UNITS + k
                                   : x + (size_t)r * IDIM + (k - UNITS);
    const float4 v0 = ((const float4*)src)[0];
    const float4 v1 = ((const float4*)src)[1];
    P8 o;
    o.e[0] = __float2bfloat16(v0.x); o.e[1] = __float2bfloat16(v0.y);
    o.e[2] = __float2bfloat16(v0.z); o.e[3] = __float2bfloat16(v0.w);
    o.e[4] = __float2bfloat16(v1.x); o.e[5] = __float2bfloat16(v1.y);
    o.e[6] = __float2bfloat16(v1.z); o.e[7] = __float2bfloat16(v1.w);
    *(bf16x8*)(A + (size_t)r * KTOT + k) = o.v;
  } else {
    const int b  = blockIdx.x - NBLK_A;   // 0..3071
    const int kb = b >> 7;                // 0..23
    const int nb = b & 127;               // 0..127
    const int k0 = kb * 64, n0 = nb * 32;
    const int n4 = (tid & 7) * 4;
    const int kk = tid >> 3;              // 0..31
#pragma unroll
    for (int rr = 0; rr < 64; rr += 32) {
      const float4 v = *(const float4*)(W + (size_t)(k0 + kk + rr) * NGATE + n0 + n4);
      tile[n4 + 0][kk + rr] = v.x; tile[n4 + 1][kk + rr] = v.y;
      tile[n4 + 2][kk + rr] = v.z; tile[n4 + 3][kk + rr] = v.w;
    }
    __syncthreads();
    const int n  = tid >> 3;
    const int k8 = (tid & 7) * 8;
    P8 o;
#pragma unroll
    for (int j = 0; j < 8; ++j) o.e[j] = __float2bfloat16(tile[n][k8 + j]);
    *(bf16x8*)(Wt + (size_t)(n0 + n) * KTOT + k0 + k8) = o.v;
  }
}

// ---------------------------------------------------------------------------
// GEMM + fused LSTM, counted-vmcnt K-half pipeline (T3/T4).
//
// Grid 512 (2 blocks/CU). Block tile 128 rows x 32 units (x4 gates = 128
// virtual cols); 4 waves 2x2, wave = 64x64, acc[4][4]. All 4 gates in-lane
// -> register-local LSTM epilogue.
//
// NEW vs dbuf __syncthreads() version: each K=64 stage is split into two
// K=32 halves; per half: raw s_barrier + s_waitcnt vmcnt(8) (never 0 in the
// steady loop) so 8-12 global_load_lds stay in flight ACROSS barriers.
// Issue order per wave: H0(it),H1(it),H0(it+1),H1(it+1) => vmcnt(8) before
// barX retires exactly the half about to be read. WAR: H0(it+1) writes buf^1
// khalf0 whose readers (t0 of it-1) all passed bar2(it-1); H1(it+1) issues
// after bar1(it) whose readers (t1 of it-1) all passed bar1(it). Safe.
//
// LDS 64 KB: A [buf][khalf][128 rows][4 slot16B], B same at +32768.
// 4-slot swizzle slot = quad ^ (m16&3) ^ ((m16>>2)&3): enumerated 2 lanes
// per 4-bank group within each 16-lane quad => conflict-free b128 reads
// (same property as the old 8-slot XOR that measured 0 conflicts).
// Source-side pre-swizzle keeps global_load_lds dest linear (m104/m173).
//
// setprio(1) around MFMA cluster: this structure has the phase role-split
// that made T5 pay on 8-phase GEMM (m218b/m224); null-risk only.
// Peeled last iter prefetches c_tm1 into regs (vmcnt 20/16 folds the 16
// extra loads into the count), hiding ~900cy HBM latency under 2 phases.
// ---------------------------------------------------------------------------
__global__ __launch_bounds__(256, 2) void lstm_gemm(
    const __hip_bfloat16* __restrict__ A,
    const __hip_bfloat16* __restrict__ Wt,
    const float* __restrict__ c_tm1,
    float* __restrict__ out) {
  __shared__ __attribute__((aligned(128))) char lds[4 * 16384];  // A0 A1 B0 B1

  const int tid  = threadIdx.x;
  const int w    = tid >> 6;     // wave 0..3 (uniform)
  const int lane = tid & 63;
  const int quad = lane >> 4;
  const int m16  = lane & 15;
  const int wr   = w >> 1;       // row half (0,1)
  const int wu   = w & 1;        // unit half (0,1)

  const int mb = blockIdx.x >> 5;   // 0..15
  const int ub = blockIdx.x & 31;   // 0..31  (XCD = ub % 8)
  const int m0 = mb * 128;
  const int u0 = ub * 32;

  // Staging: per K-half, 1024 16B chunks (A 512 + B 512) / 256 thr = 4 each.
  const __hip_bfloat16* ptr[4];
  int dst[4];
#pragma unroll
  for (int s = 0; s < 4; ++s) {
    const int q  = s * 4 + w;             // wave-uniform 0..15
    const int ci = (q & 7) * 64 + lane;   // chunk 0..511 within A- or B-half
    const int row = ci >> 2;              // 0..127
    const int sl  = ci & 3;
    const int xs  = (row & 3) ^ ((row >> 2) & 3);
    const int k8  = sl ^ xs;              // local k-chunk 0..3 within half
    if (q < 8) {   // A half-tile
      ptr[s] = A + (size_t)(m0 + row) * KTOT + k8 * 8;
      dst[s] = q * 1024;                  // within A buf0 half0
    } else {       // B half-tile: virtual col row -> Wt row
      const int wrow = ((row >> 5) << 10) + u0 + (row & 31);
      ptr[s] = Wt + (size_t)wrow * KTOT + k8 * 8;
      dst[s] = 32768 + (q - 8) * 1024;    // within B buf0 half0
    }
  }

  auto issue = [&](int koffE, int ldsOff) {
#pragma unroll
    for (int s = 0; s < 4; ++s)
      __builtin_amdgcn_global_load_lds(AS1(ptr[s] + koffE),
                                       AS3(lds + dst[s] + ldsOff), 16, 0, 0);
  };

  // fragment-read byte offsets (per-lane constant; slot same for all frags)
  const int x16  = (m16 & 3) ^ ((m16 >> 2) & 3);
  const int sA   = quad ^ x16;
  const int aoff = (wr * 64 + m16) * 64 + sA * 16;
  const int boff = 32768 + (wu * 16 + m16) * 64 + sA * 16;

  f32x4 acc[4][4];
#pragma unroll
  for (int i = 0; i < 4; ++i)
#pragma unroll
    for (int g = 0; g < 4; ++g) {
      f32x4 z = {0.f, 0.f, 0.f, 0.f};
      acc[i][g] = z;
    }

  auto compute = [&](int coff) {   // coff = buf*16384 + khalf*8192
    bf16x8 a[4], b[4];
    const char* ab = lds + coff + aoff;
    const char* bb = lds + coff + boff;
#pragma unroll
    for (int i = 0; i < 4; ++i) a[i] = *(const bf16x8*)(ab + i * 1024);
#pragma unroll
    for (int g = 0; g < 4; ++g) b[g] = *(const bf16x8*)(bb + g * 2048);
    __builtin_amdgcn_s_setprio(1);
#pragma unroll
    for (int g = 0; g < 4; ++g)
#pragma unroll
      for (int i = 0; i < 4; ++i)
        acc[i][g] = __builtin_amdgcn_mfma_f32_16x16x32_bf16(a[i], b[g], acc[i][g], 0, 0, 0);
    __builtin_amdgcn_s_setprio(0);
  };

#define WAITB(N)                                          \
  asm volatile("s_waitcnt vmcnt(" #N ")" ::: "memory");   \
  __builtin_amdgcn_s_barrier();                           \
  asm volatile("" ::: "memory");

  // prologue: stage iter 0 (both halves) into buffer 0
  issue(0, 0);
  issue(32, 8192);

  for (int it = 0; it < NITER - 1; ++it) {
    const int coff = (it & 1) * 16384;
    const int noff = coff ^ 16384;
    const int ke   = (it + 1) * BK;
    issue(ke, noff);                 // H0(it+1)
    WAITB(8)                         // H0(it) retired; publish
    issue(ke + 32, noff + 8192);     // H1(it+1) (safe: all waves past bar1)
    compute(coff);                   // khalf 0
    WAITB(8)                         // H1(it) retired; publish
    compute(coff + 8192);            // khalf 1
  }

  // peeled last iter (it = NITER-1, buf = 1): fold c_tm1 prefetch into count
  const int u = u0 + wu * 16 + m16;
  float cpre[4][4];
#pragma unroll
  for (int i = 0; i < 4; ++i)
#pragma unroll
    for (int reg = 0; reg < 4; ++reg) {
      const int r = m0 + wr * 64 + i * 16 + quad * 4 + reg;
      cpre[i][reg] = c_tm1[(size_t)r * UNITS + u];
    }
  // outstanding: H0(L)4 + H1(L)4 + c 16 = 24
  WAITB(20)                          // H0(L) retired
  compute(((NITER - 1) & 1) * 16384);
  WAITB(16)                          // H1(L) retired
  compute(((NITER - 1) & 1) * 16384 + 8192);

#undef WAITB

  // fused LSTM epilogue -- all 4 gates in-lane
#pragma unroll
  for (int i = 0; i < 4; ++i)
#pragma unroll
    for (int reg = 0; reg < 4; ++reg) {
      const int r = m0 + wr * 64 + i * 16 + quad * 4 + reg;
      const float z0 = acc[i][0][reg];   // gate i
      const float z1 = acc[i][1][reg];   // gate f
      const float z2 = acc[i][2][reg];   // c_tilde
      const float z3 = acc[i][3][reg];   // gate o
      const float ig = 1.f / (1.f + __expf(-z0));
      const float fg = 1.f / (1.f + __expf(-z1));
      const float ct = 1.f - 2.f / (__expf(2.f * z2) + 1.f);   // tanh, inf-safe
      const float og = 1.f / (1.f + __expf(-z3));
      const float cc = fg * cpre[i][reg] + ig * ct;
      const float hh = og * (1.f - 2.f / (__expf(2.f * cc) + 1.f));
      out[(size_t)r * UNITS + u] = hh;
      out[(size_t)BATCH * UNITS + (size_t)r * UNITS + u] = cc;
    }
}

// ---------------------------------------------------------------------------
// Fallback (only if d_ws too small): naive fp32, correct but slow.
// ---------------------------------------------------------------------------
__global__ __launch_bounds__(256) void lstm_naive(
    const float* __restrict__ x, const float* __restrict__ h,
    const float* __restrict__ c_tm1, const float* __restrict__ W,
    float* __restrict__ out) {
  int idx = blockIdx.x * 256 + threadIdx.x;
  int r = idx / UNITS;
  int u = idx % UNITS;
  float z[4] = {0.f, 0.f, 0.f, 0.f};
  for (int k = 0; k < KTOT; ++k) {
    float a = (k < UNITS) ? h[(size_t)r * UNITS + k] : x[(size_t)r * IDIM + k - UNITS];
#pragma unroll
    for (int g = 0; g < 4; ++g)
      z[g] += a * W[(size_t)k * NGATE + g * UNITS + u];
  }
  float ig = 1.f / (1.f + __expf(-z[0]));
  float fg = 1.f / (1.f + __expf(-z[1]));
  float ct = 1.f - 2.f / (__expf(2.f * z[2]) + 1.f);
  float og = 1.f / (1.f + __expf(-z[3]));
  float cc = fg * c_tm1[(size_t)r * UNITS + u] + ig * ct;
  float hh = og * (1.f - 2.f / (__expf(2.f * cc) + 1.f));
  out[(size_t)r * UNITS + u] = hh;
  out[(size_t)BATCH * UNITS + (size_t)r * UNITS + u] = cc;
}

extern "C" void kernel_launch(void* const* d_in, const int* in_sizes, int n_in,
                              void* d_out, int out_size, void* d_ws, size_t ws_size,
                              hipStream_t stream) {
  const float* x = (const float*)d_in[0];   // [2048][512]
  const float* h = (const float*)d_in[1];   // [2048][1024]
  const float* c = (const float*)d_in[2];   // [2048][1024]
  const float* W = (const float*)d_in[3];   // [1536][4096]
  float* out = (float*)d_out;               // h then c, 2 x [2048][1024]

  const size_t needA  = (size_t)BATCH * KTOT * sizeof(__hip_bfloat16);  // 6.29 MB
  const size_t needWt = (size_t)NGATE * KTOT * sizeof(__hip_bfloat16);  // 12.58 MB
  if (ws_size < needA + needWt) {
    hipLaunchKernelGGL(lstm_naive, dim3((BATCH * UNITS) / 256), dim3(256), 0, stream,
                       x, h, c, W, out);
    return;
  }

  __hip_bfloat16* A  = (__hip_bfloat16*)d_ws;
  __hip_bfloat16* Wt = (__hip_bfloat16*)((char*)d_ws + needA);

  hipLaunchKernelGGL(prep, dim3(NBLK_A + NBLK_T), dim3(256), 0, stream, x, h, W, A, Wt);
  hipLaunchKernelGGL(lstm_gemm, dim3(512), dim3(256), 0, stream, A, Wt, c, out);
}

// Round 2
// 121.720 us; speedup vs baseline: 1.0311x; 1.0311x over previous
//
#include <hip/hip_runtime.h>
#include <hip/hip_bf16.h>
#include <stdint.h>

#define UNITS 1024
#define IDIM  512
#define BATCH 2048
#define KTOT  1536   // UNITS + IDIM
#define NGATE 4096   // 4*UNITS
#define BK    64
#define NITER (KTOT / BK)   // 24

typedef short bf16x8 __attribute__((ext_vector_type(8)));   // 8 bf16 = 4 VGPRs
typedef float f32x4  __attribute__((ext_vector_type(4)));

#define AS3(p) ((__attribute__((address_space(3))) void*)(p))
#define AS1(p) ((const __attribute__((address_space(1))) void*)(p))

union P8 { bf16x8 v; __hip_bfloat16 e[8]; };

// ---------------------------------------------------------------------------
// prep: blocks [0,1536) cast-concat A = bf16(concat[h,x]); blocks [1536,4608)
// transpose W fp32 [1536][4096] -> Wt bf16 [4096][1536] (k-contiguous rows).
// ---------------------------------------------------------------------------
#define NBLK_A 1536
#define NBLK_T 3072

__global__ __launch_bounds__(256) void prep(
    const float* __restrict__ x, const float* __restrict__ h,
    const float* __restrict__ W,
    __hip_bfloat16* __restrict__ A, __hip_bfloat16* __restrict__ Wt) {
  __shared__ float tile[32][65];
  const int tid = threadIdx.x;
  if (blockIdx.x < NBLK_A) {
    const int id = blockIdx.x * 256 + tid;
    const int r = id / (KTOT / 8);
    const int k = (id % (KTOT / 8)) * 8;
    const float* src = (k < UNITS) ? h + (size_t)r * UNITS + k
                                   : x + (size_t)r * IDIM + (k - UNITS);
    const float4 v0 = ((const float4*)src)[0];
    const float4 v1 = ((const float4*)src)[1];
    P8 o;
    o.e[0] = __float2bfloat16(v0.x); o.e[1] = __float2bfloat16(v0.y);
    o.e[2] = __float2bfloat16(v0.z); o.e[3] = __float2bfloat16(v0.w);
    o.e[4] = __float2bfloat16(v1.x); o.e[5] = __float2bfloat16(v1.y);
    o.e[6] = __float2bfloat16(v1.z); o.e[7] = __float2bfloat16(v1.w);
    *(bf16x8*)(A + (size_t)r * KTOT + k) = o.v;
  } else {
    const int b  = blockIdx.x - NBLK_A;   // 0..3071
    const int kb = b >> 7;                // 0..23
    const int nb = b & 127;               // 0..127
    const int k0 = kb * 64, n0 = nb * 32;
    const int n4 = (tid & 7) * 4;
    const int kk = tid >> 3;              // 0..31
#pragma unroll
    for (int rr = 0; rr < 64; rr += 32) {
      const float4 v = *(const float4*)(W + (size_t)(k0 + kk + rr) * NGATE + n0 + n4);
      tile[n4 + 0][kk + rr] = v.x; tile[n4 + 1][kk + rr] = v.y;
      tile[n4 + 2][kk + rr] = v.z; tile[n4 + 3][kk + rr] = v.w;
    }
    __syncthreads();
    const int n  = tid >> 3;
    const int k8 = (tid & 7) * 8;
    P8 o;
#pragma unroll
    for (int j = 0; j < 8; ++j) o.e[j] = __float2bfloat16(tile[n][k8 + j]);
    *(bf16x8*)(Wt + (size_t)(n0 + n) * KTOT + k0 + k8) = o.v;
  }
}

// ---------------------------------------------------------------------------
// GEMM + fused LSTM -- R2: occupancy doubled vs the 256-thread version.
//
// 512 threads / 8 waves per block, grid 512 (2 blocks/CU -> 16 waves/CU =
// 4 waves/SIMD, up from 2). LDS unchanged at 64 KB/block (the cap: 128 KB
// of 160 KB/CU). R1 lesson: the gemm was 55% stall at Occupancy=14.9% --
// latency hiding, not pipeline structure, is the binding constraint at this
// tile size (counted-vmcnt restructure measured neutral once its bank
// conflicts (~5 us, 3.1M cycles) were backed out).
//
// Block tile: 128 rows x 32 units (x4 gates = 128 virtual cols). 8 waves
// tile 4(row) x 2(unit): wave = 32 rows x 16 units x 4 gates -> acc[2][4]
// (32 VGPR). All 4 gates in-lane -> register-local LSTM epilogue.
//
// LDS layout (PROVEN 0-conflict in earlier rounds -- do not re-derive):
// per tile [128 rows][8 chunks of 16B], 16B chunks XOR-swizzled
// chunk(row,k8) = row*8 + (k8 ^ (row&7)); ds_read_b128 slot = (t*4+quad) ^
// (row&7) -> 2 lanes/bank (free, m136). Source-side pre-swizzle keeps the
// global_load_lds destination linear (m104/m173).
//
// A AND B double-buffered (4 x 16 KB): prefetch iter k+1 via
// global_load_lds(width=16) BEFORE computing iter k, one __syncthreads/iter.
// XCD: XCD = bi%8 = ub%8 -> all 16 mb-blocks sharing a ub B-slice land on
// one XCD (B slice 384 KB bf16, L2-resident).
// ---------------------------------------------------------------------------
__global__ __launch_bounds__(512, 4) void lstm_gemm(
    const __hip_bfloat16* __restrict__ A,
    const __hip_bfloat16* __restrict__ Wt,
    const float* __restrict__ c_tm1,
    float* __restrict__ out) {
  __shared__ __attribute__((aligned(128))) char lds[4 * 16384];  // A0 A1 B0 B1

  const int tid  = threadIdx.x;
  const int w    = tid >> 6;     // wave 0..7 (uniform)
  const int lane = tid & 63;
  const int quad = lane >> 4;
  const int m16  = lane & 15;
  const int wr4  = w >> 1;       // row quarter (0..3)
  const int wu   = w & 1;        // unit half (0,1)

  const int mb = blockIdx.x >> 5;   // 0..15
  const int ub = blockIdx.x & 31;   // 0..31  (XCD = ub % 8)
  const int m0 = mb * 128;
  const int u0 = ub * 32;

  // Staging: 2048 16B chunks per iter (A 1024 + B 1024) / 512 thr = 4 each.
  const __hip_bfloat16* ptr[4];
  int dst[4];
#pragma unroll
  for (int s = 0; s < 4; ++s) {
    const int q  = s * 8 + w;              // wave-uniform 0..31
    const int ci = (q & 15) * 64 + lane;   // chunk 0..1023 within tile
    const int row = ci >> 3;               // 0..127
    const int k8  = (ci & 7) ^ (row & 7);  // source-side swizzle
    if (q < 16) {   // A tile
      ptr[s] = A + (size_t)(m0 + row) * KTOT + k8 * 8;
      dst[s] = q * 1024;                   // within A buffer
    } else {        // B tile: virtual col row -> Wt row
      const int wrow = ((row >> 5) << 10) + u0 + (row & 31);
      ptr[s] = Wt + (size_t)wrow * KTOT + k8 * 8;
      dst[s] = 32768 + (q - 16) * 1024;    // within B buffer 0
    }
  }

  f32x4 acc[2][4];
#pragma unroll
  for (int i = 0; i < 2; ++i)
#pragma unroll
    for (int g = 0; g < 4; ++g) {
      f32x4 z = {0.f, 0.f, 0.f, 0.f};
      acc[i][g] = z;
    }

  // prologue: stage iter 0 into buffer 0
#pragma unroll
  for (int s = 0; s < 4; ++s)
    __builtin_amdgcn_global_load_lds(AS1(ptr[s]), AS3(lds + dst[s]), 16, 0, 0);
  __syncthreads();

  for (int it = 0; it < NITER; ++it) {
    const int cur = it & 1;
    const int nxt = cur ^ 1;
    // prefetch iter it+1 into buffers `nxt`
    if (it < NITER - 1) {
      const int koff = (it + 1) * BK;
#pragma unroll
      for (int s = 0; s < 4; ++s)
        __builtin_amdgcn_global_load_lds(AS1(ptr[s] + koff),
                                         AS3(lds + dst[s] + nxt * 16384), 16, 0, 0);
    }
    // compute iter `it` from buffers `cur`
    const char* abuf = lds + cur * 16384;
    const char* bbuf = lds + 32768 + cur * 16384;
#pragma unroll
    for (int t = 0; t < 2; ++t) {
      bf16x8 a[2], b[4];
#pragma unroll
      for (int i = 0; i < 2; ++i) {
        const int row  = wr4 * 32 + i * 16 + m16;
        const int slot = (t * 4 + quad) ^ (row & 7);
        a[i] = *(const bf16x8*)(abuf + (row * 8 + slot) * 16);
      }
#pragma unroll
      for (int g = 0; g < 4; ++g) {
        const int vr   = g * 32 + wu * 16 + m16;
        const int slot = (t * 4 + quad) ^ (vr & 7);
        b[g] = *(const bf16x8*)(bbuf + (vr * 8 + slot) * 16);
      }
#pragma unroll
      for (int g = 0; g < 4; ++g)
#pragma unroll
        for (int i = 0; i < 2; ++i)
          acc[i][g] = __builtin_amdgcn_mfma_f32_16x16x32_bf16(a[i], b[g], acc[i][g], 0, 0, 0);
    }
    __syncthreads();   // drains prefetch writes + fences reads of `cur`
  }

  // fused LSTM epilogue -- all 4 gates in-lane
  const int u = u0 + wu * 16 + m16;
#pragma unroll
  for (int i = 0; i < 2; ++i)
#pragma unroll
    for (int reg = 0; reg < 4; ++reg) {
      const int r = m0 + wr4 * 32 + i * 16 + quad * 4 + reg;
      const float z0 = acc[i][0][reg];   // gate i
      const float z1 = acc[i][1][reg];   // gate f
      const float z2 = acc[i][2][reg];   // c_tilde
      const float z3 = acc[i][3][reg];   // gate o
      const float ig = 1.f / (1.f + __expf(-z0));
      const float fg = 1.f / (1.f + __expf(-z1));
      const float ct = 1.f - 2.f / (__expf(2.f * z2) + 1.f);   // tanh, inf-safe
      const float og = 1.f / (1.f + __expf(-z3));
      const float cc = fg * c_tm1[(size_t)r * UNITS + u] + ig * ct;
      const float hh = og * (1.f - 2.f / (__expf(2.f * cc) + 1.f));
      out[(size_t)r * UNITS + u] = hh;
      out[(size_t)BATCH * UNITS + (size_t)r * UNITS + u] = cc;
    }
}

// ---------------------------------------------------------------------------
// Fallback (only if d_ws too small): naive fp32, correct but slow.
// ---------------------------------------------------------------------------
__global__ __launch_bounds__(256) void lstm_naive(
    const float* __restrict__ x, const float* __restrict__ h,
    const float* __restrict__ c_tm1, const float* __restrict__ W,
    float* __restrict__ out) {
  int idx = blockIdx.x * 256 + threadIdx.x;
  int r = idx / UNITS;
  int u = idx % UNITS;
  float z[4] = {0.f, 0.f, 0.f, 0.f};
  for (int k = 0; k < KTOT; ++k) {
    float a = (k < UNITS) ? h[(size_t)r * UNITS + k] : x[(size_t)r * IDIM + k - UNITS];
#pragma unroll
    for (int g = 0; g < 4; ++g)
      z[g] += a * W[(size_t)k * NGATE + g * UNITS + u];
  }
  float ig = 1.f / (1.f + __expf(-z[0]));
  float fg = 1.f / (1.f + __expf(-z[1]));
  float ct = 1.f - 2.f / (__expf(2.f * z[2]) + 1.f);
  float og = 1.f / (1.f + __expf(-z[3]));
  float cc = fg * c_tm1[(size_t)r * UNITS + u] + ig * ct;
  float hh = og * (1.f - 2.f / (__expf(2.f * cc) + 1.f));
  out[(size_t)r * UNITS + u] = hh;
  out[(size_t)BATCH * UNITS + (size_t)r * UNITS + u] = cc;
}

extern "C" void kernel_launch(void* const* d_in, const int* in_sizes, int n_in,
                              void* d_out, int out_size, void* d_ws, size_t ws_size,
                              hipStream_t stream) {
  const float* x = (const float*)d_in[0];   // [2048][512]
  const float* h = (const float*)d_in[1];   // [2048][1024]
  const float* c = (const float*)d_in[2];   // [2048][1024]
  const float* W = (const float*)d_in[3];   // [1536][4096]
  float* out = (float*)d_out;               // h then c, 2 x [2048][1024]

  const size_t needA  = (size_t)BATCH * KTOT * sizeof(__hip_bfloat16);  // 6.29 MB
  const size_t needWt = (size_t)NGATE * KTOT * sizeof(__hip_bfloat16);  // 12.58 MB
  if (ws_size < needA + needWt) {
    hipLaunchKernelGGL(lstm_naive, dim3((BATCH * UNITS) / 256), dim3(256), 0, stream,
                       x, h, c, W, out);
    return;
  }

  __hip_bfloat16* A  = (__hip_bfloat16*)d_ws;
  __hip_bfloat16* Wt = (__hip_bfloat16*)((char*)d_ws + needA);

  hipLaunchKernelGGL(prep, dim3(NBLK_A + NBLK_T), dim3(256), 0, stream, x, h, W, A, Wt);
  hipLaunchKernelGGL(lstm_gemm, dim3(512), dim3(512), 0, stream, A, Wt, c, out);
}